// Round 10
// baseline (317.735 us; speedup 1.0000x reference)
//
#include <hip/hip_runtime.h>
#include <hip/hip_bf16.h>
#include <hip/hip_cooperative_groups.h>

// LPLayer: e = x@W^T + b; lp = relu(tanh(e@e^T)); nf = lp@e / N
// B=8, N=2048, C_IN=128, D(C_OUT)=64. All I/O **fp32** (reference dtypes).
// d_out (float) = [nf (8*2048*64)] ++ [lp (8*2048*2048)]

#define B_    8
#define N_    2048
#define D_    64
#define CIN_  128

typedef __bf16 bf16x8 __attribute__((ext_vector_type(8)));
typedef float f32x4  __attribute__((ext_vector_type(4)));

union FragU { uint4 u; bf16x8 f; };

static __device__ __forceinline__ bf16x8 ld_frag(const __hip_bfloat16* p) {
    FragU fu; fu.u = *reinterpret_cast<const uint4*>(p); return fu.f;
}

static __device__ __forceinline__ void st_frag(__hip_bfloat16* p, bf16x8 f) {
    FragU fu; fu.f = f; *reinterpret_cast<uint4*>(p) = fu.u;
}

// Split 8 consecutive fp32 into hi/lo bf16x8 (hi = RTN(v), lo = RTN(v - hi)).
static __device__ __forceinline__ void split8(const float* p, bf16x8& hi, bf16x8& lo) {
    const float4 a = *reinterpret_cast<const float4*>(p);
    const float4 b = *reinterpret_cast<const float4*>(p + 4);
    const float v[8] = {a.x, a.y, a.z, a.w, b.x, b.y, b.z, b.w};
#pragma unroll
    for (int i = 0; i < 8; i++) {
        const __bf16 h = (__bf16)v[i];
        hi[i] = h;
        lo[i] = (__bf16)(v[i] - (float)h);
    }
}

// Convert 8 consecutive fp32 (LDS) to bf16x8.
static __device__ __forceinline__ bf16x8 cvt8(const float* p) {
    const float4 a = *reinterpret_cast<const float4*>(p);
    const float4 b = *reinterpret_cast<const float4*>(p + 4);
    bf16x8 r;
    r[0] = (__bf16)a.x; r[1] = (__bf16)a.y; r[2] = (__bf16)a.z; r[3] = (__bf16)a.w;
    r[4] = (__bf16)b.x; r[5] = (__bf16)b.y; r[6] = (__bf16)b.z; r[7] = (__bf16)b.w;
    return r;
}

// Barrier that waits ONLY on LDS ops (lgkmcnt), never vmcnt: in-flight
// prefetch loads and NT store drains survive across it. sched_barrier(0)
// stops post-barrier LDS reads hoisting above (rule #18).
static __device__ __forceinline__ void lds_barrier() {
    asm volatile("s_waitcnt lgkmcnt(0)" ::: "memory");
    __builtin_amdgcn_s_barrier();
    __builtin_amdgcn_sched_barrier(0);
}

#define LDW  136  // W LDS row stride, bf16 (128 + 8 pad -> 2-way banks)
#define LDE  72   // E tile LDS row stride, bf16 (64 + 8 pad)
#define LDT  136  // EhiT LDS row stride, bf16 (128 + 8 pad)
#define LDF  132  // lp tile LDS row stride, fp32 (128 + 4 pad, 16B-mult)

// ---------------------------------------------------------------------------
// v11: MERGED cooperative kernel = v10's two dispatches in one launch.
// v10 decomposition (stable across rounds 2-8): fill ~86 us (harness) + ex ~5
// + fused ~49 + launch/dispatch gaps ~31. The merge deletes the ex->fused
// dispatch boundary (~10 us/dispatch per rocprof.md launch-overhead note).
// Phase 1 (ex): each block computes e for ITS OWN 32 i-rows of batch b
//   (512 blocks x 32 rows = all 16384 rows; W hi/lo split staged per block).
// __threadfence + grid.sync(): e visible device-wide. Note batch-b panel
//   writers (b, 0..63) have linear id = b+8y -> same XCD (id%8) -> panel
//   reads in phase 2 are same-XCD L2 hits; the fence covers the general case.
// Phase 2: v10 fused body verbatim (T14 reg-staged panels, lgkm-only
//   barriers, NT 512B-chunk lp stores, PV self-read, LDS h-reduce epilogue).
// Co-residency for cooperative launch: LDS 71,168 B -> exactly 2 blocks/CU
//   x 256 CU = 512 blocks. VGPR ~64-80 -> no occupancy constraint.
// kernel_launch hedges: if hipLaunchCooperativeKernel errors, falls back to
//   the proven two-kernel v10 path.
// ---------------------------------------------------------------------------
__global__ __launch_bounds__(512, 4) void merged_kernel(
    const float* __restrict__ x,
    const float* __restrict__ W,
    const float* __restrict__ bias,
    __hip_bfloat16* __restrict__ e_hi,
    __hip_bfloat16* __restrict__ e_lo,
    __hip_bfloat16* __restrict__ e_hiT,
    float* __restrict__ out)
{
    // 16896 (sLpF) + 18432*2 (sEhi/sElo) + 17408 (sEhiT) = 71,168 B.
    // Phase 1 overlays the W hi/lo staging (34,816 B) on the same region.
    __shared__ __align__(16) unsigned char smem[32 * LDF * 4 + 128 * LDE * 2 * 2 + 64 * LDT * 2];

    const int b   = blockIdx.x;          // batch (linear id % 8: XCD-aligned)
    const int i0  = blockIdx.y * 32;
    const int tid = threadIdx.x;
    const int w = tid >> 6, lane = tid & 63, quad = lane >> 4, l16 = lane & 15;
    const int g = w >> 2, h = w & 3;
    const int m0 = i0 + g * 16;
    const int koff = h * 32 + quad * 8;  // wave's j/k quarter offset (phase 2)

    // ===================== PHASE 1: e = x @ W^T + b ========================
    {
        __hip_bfloat16* sWhi = (__hip_bfloat16*)smem;
        __hip_bfloat16* sWlo = sWhi + 64 * LDW;

        // stage W split into LDS: 64 rows x 128 = 1024 chunks, 2 per thread
#pragma unroll
        for (int p = 0; p < 2; p++) {
            const int q = tid + p * 512;
            const int r = q >> 4, c = (q & 15) * 8;
            bf16x8 hi, lo;
            split8(W + (size_t)r * CIN_ + c, hi, lo);
            st_frag(sWhi + r * LDW + c, hi);
            st_frag(sWlo + r * LDW + c, lo);
        }
        __syncthreads();

        // wave (g,h): rows m0..m0+15, chans h*16..+15 (1 nt tile per wave)
        const float* xrow = x + (size_t)(b * N_ + m0 + l16) * CIN_;
        bf16x8 ah[4], al[4];
#pragma unroll
        for (int ks = 0; ks < 4; ks++)
            split8(xrow + ks * 32 + quad * 8, ah[ks], al[ks]);

        const int chan = h * 16 + l16;
        f32x4 acc = f32x4{0.f, 0.f, 0.f, 0.f};
#pragma unroll
        for (int ks = 0; ks < 4; ks++) {
            bf16x8 wh = ld_frag(sWhi + chan * LDW + ks * 32 + quad * 8);
            bf16x8 wl = ld_frag(sWlo + chan * LDW + ks * 32 + quad * 8);
            acc = __builtin_amdgcn_mfma_f32_16x16x32_bf16(ah[ks], wh, acc, 0, 0, 0);
            acc = __builtin_amdgcn_mfma_f32_16x16x32_bf16(ah[ks], wl, acc, 0, 0, 0);
            acc = __builtin_amdgcn_mfma_f32_16x16x32_bf16(al[ks], wh, acc, 0, 0, 0);
        }

        // epilogue: bias, hi/lo split, stores (C/D: col=chan, row=quad*4+i)
        const float bv = bias[chan];
        union { __hip_bfloat16 hh[4]; uint2 u2; } hv;
#pragma unroll
        for (int i = 0; i < 4; i++) {
            const int gr = b * N_ + m0 + quad * 4 + i;
            const float e = acc[i] + bv;
            const __hip_bfloat16 hi = __float2bfloat16(e);
            const __hip_bfloat16 lo = __float2bfloat16(e - __bfloat162float(hi));
            e_hi[(size_t)gr * D_ + chan] = hi;
            e_lo[(size_t)gr * D_ + chan] = lo;
            hv.hh[i] = hi;
        }
        const int ir = m0 + quad * 4;    // 4 consecutive rows, one 8 B store
        *reinterpret_cast<uint2*>(e_hiT + ((size_t)(b * D_ + chan)) * N_ + ir) = hv.u2;
        __syncthreads();   // phase-1 LDS (sW) dead before phase-2 reuse
    }

    __threadfence();                        // device-scope release of e writes
    cooperative_groups::this_grid().sync(); // all e complete, visible

    // ===================== PHASE 2: fused (v10 body) =======================
    float*          sLpF  = (float*)smem;                           // [32][132]
    __hip_bfloat16* sEhi  = (__hip_bfloat16*)(smem + 32 * LDF * 4); // [128][72]
    __hip_bfloat16* sElo  = sEhi + 128 * LDE;                       // [128][72]
    __hip_bfloat16* sEhiT = sElo + 128 * LDE;                       // [64][136]

    // Per-thread staging chunk assignments (1024 chunks of 16 B per array).
    const int q2 = tid + 512;
    const int er1 = tid >> 3, ec1 = (tid & 7) * 8;   // Ehi/Elo chunk 1
    const int er2 = q2  >> 3, ec2 = (q2  & 7) * 8;   // Ehi/Elo chunk 2
    const int tr1 = tid >> 4, tc1 = (tid & 15) * 8;  // EhiT chunk 1
    const int tr2 = q2  >> 4, tc2 = (q2  & 15) * 8;  // EhiT chunk 2

    // Persistent Ei A-frags (hi & lo), K=64 -> 2 ksteps (own rows, L2-hot)
    const __hip_bfloat16* eih = e_hi + (size_t)(b * N_ + m0 + l16) * D_;
    const __hip_bfloat16* eil = e_lo + (size_t)(b * N_ + m0 + l16) * D_;
    bf16x8 ahi[2], alo[2];
#pragma unroll
    for (int ks = 0; ks < 2; ks++) {
        ahi[ks] = ld_frag(eih + ks * 32 + quad * 8);
        alo[ks] = ld_frag(eil + ks * 32 + quad * 8);
    }

    f32x4 o[4];
#pragma unroll
    for (int nt = 0; nt < 4; nt++) o[nt] = f32x4{0.f, 0.f, 0.f, 0.f};

    float* lp_out = out + (size_t)B_ * N_ * D_;

    // preload staged panel regs for jt = 0
    uint4 gh0, gh1, gl0, gl1, gt0, gt1;
    {
        gh0 = *(const uint4*)(e_hi + (size_t)(b * N_ + er1) * D_ + ec1);
        gh1 = *(const uint4*)(e_hi + (size_t)(b * N_ + er2) * D_ + ec2);
        gl0 = *(const uint4*)(e_lo + (size_t)(b * N_ + er1) * D_ + ec1);
        gl1 = *(const uint4*)(e_lo + (size_t)(b * N_ + er2) * D_ + ec2);
        gt0 = *(const uint4*)(e_hiT + (size_t)(b * D_ + tr1) * N_ + tc1);
        gt1 = *(const uint4*)(e_hiT + (size_t)(b * D_ + tr2) * N_ + tc2);
    }

    for (int jt = 0; jt < 16; jt++) {
        lds_barrier();   // Ba: jt-1's panel reads + trans writes complete

        // ---- lp(jt-1) -> global NT (512 B chunks), || with panel ds_write ----
        if (jt > 0) {
            const int jc0 = (jt - 1) * 128;
#pragma unroll
            for (int p = 0; p < 2; p++) {
                const int q = tid + p * 512;          // 0..1023
                const int r = q >> 5, c = (q & 31) * 4;
                __builtin_nontemporal_store(
                    *(const f32x4*)(sLpF + r * LDF + c),
                    (f32x4*)(lp_out + ((size_t)(b * N_ + i0 + r)) * N_ + jc0 + c));
            }
        }

        // ---- ds_write staged panel jt (counted vmcnt on reg deps) ----
        *(uint4*)(sEhi  + er1 * LDE + ec1) = gh0;
        *(uint4*)(sEhi  + er2 * LDE + ec2) = gh1;
        *(uint4*)(sElo  + er1 * LDE + ec1) = gl0;
        *(uint4*)(sElo  + er2 * LDE + ec2) = gl1;
        *(uint4*)(sEhiT + tr1 * LDT + tc1) = gt0;
        *(uint4*)(sEhiT + tr2 * LDT + tc2) = gt1;

        lds_barrier();   // Bb: panel jt visible; store-reads of jt-1 done

        // ---- issue staged loads for jt+1 (in flight through Gram/trans/PV) ----
        {
            const int j0n = ((jt + 1) & 15) * 128;    // wrap: harmless prefetch
            gh0 = *(const uint4*)(e_hi + (size_t)(b * N_ + j0n + er1) * D_ + ec1);
            gh1 = *(const uint4*)(e_hi + (size_t)(b * N_ + j0n + er2) * D_ + ec2);
            gl0 = *(const uint4*)(e_lo + (size_t)(b * N_ + j0n + er1) * D_ + ec1);
            gl1 = *(const uint4*)(e_lo + (size_t)(b * N_ + j0n + er2) * D_ + ec2);
            gt0 = *(const uint4*)(e_hiT + (size_t)(b * D_ + tr1) * N_ + j0n + tc1);
            gt1 = *(const uint4*)(e_hiT + (size_t)(b * D_ + tr2) * N_ + j0n + tc2);
        }

        // ---- Gram: S[16 x 32] per wave from LDS, split product, tanh/relu ----
#pragma unroll
        for (int ntl = 0; ntl < 2; ntl++) {
            const int n0 = h * 32 + ntl * 16;
            f32x4 s = f32x4{0.f, 0.f, 0.f, 0.f};
#pragma unroll
            for (int ks = 0; ks < 2; ks++) {
                const int ko = ks * 32 + quad * 8;
                bf16x8 bhi = ld_frag(sEhi + (n0 + l16) * LDE + ko);
                bf16x8 blo = ld_frag(sElo + (n0 + l16) * LDE + ko);
                s = __builtin_amdgcn_mfma_f32_16x16x32_bf16(ahi[ks], bhi, s, 0, 0, 0);
                s = __builtin_amdgcn_mfma_f32_16x16x32_bf16(ahi[ks], blo, s, 0, 0, 0);
                s = __builtin_amdgcn_mfma_f32_16x16x32_bf16(alo[ks], bhi, s, 0, 0, 0);
            }
#pragma unroll
            for (int i = 0; i < 4; i++) {
                // relu(tanh(t)) = tanh(max(t,0)) — clamp BEFORE exp2: no
                // overflow path, and fmaxf(NaN,0)=0 absorbs upstream garbage.
                const float tc = fmaxf(s[i], 0.0f);
                const float z = __builtin_amdgcn_exp2f(tc * -2.8853900817779268f);
                const float v = (1.0f - z) * __builtin_amdgcn_rcpf(1.0f + z);
                sLpF[(g * 16 + quad * 4 + i) * LDF + n0 + l16] = v;
            }
        }

        // ---- PV: self-read own 16x32 block (same-wave RAW) + sEhiT frags ----
        {
            bf16x8 a = cvt8(sLpF + (g * 16 + l16) * LDF + koff);
#pragma unroll
            for (int nt = 0; nt < 4; nt++) {
                bf16x8 bfr = ld_frag(sEhiT + (nt * 16 + l16) * LDT + koff);
                o[nt] = __builtin_amdgcn_mfma_f32_16x16x32_bf16(a, bfr, o[nt], 0, 0, 0);
            }
        }
    }

    // ---- drain: store lp tile 15 ----
    lds_barrier();
    {
        const int jc0 = 15 * 128;
#pragma unroll
        for (int p = 0; p < 2; p++) {
            const int q = tid + p * 512;
            const int r = q >> 5, c = (q & 31) * 4;
            __builtin_nontemporal_store(
                *(const f32x4*)(sLpF + r * LDF + c),
                (f32x4*)(lp_out + ((size_t)(b * N_ + i0 + r)) * N_ + jc0 + c));
        }
    }
    lds_barrier();   // store-reads done before sO overlay

    // ---- epilogue: sum 4 j-quarter partials, /N, store node_feats (fp32) ----
    float* sO = (float*)smem;   // overlay (34.8 KB)
#pragma unroll
    for (int nt = 0; nt < 4; nt++) {
#pragma unroll
        for (int i = 0; i < 4; i++) {
            const int row = quad * 4 + i;            // local row in group
            const int chan = nt * 16 + l16;
            sO[w * 1088 + row * 68 + chan] = o[nt][i];   // stride 68: 2-way banks
        }
    }
    lds_barrier();
    {
        const int row = tid >> 4;                    // 0..31
        const int c4  = (tid & 15) * 4;
        const int gg = row >> 4, rr = row & 15;
        const float* base = sO + (gg * 4) * 1088 + rr * 68 + c4;
        const float4 v0 = *(const float4*)(base);
        const float4 v1 = *(const float4*)(base + 1088);
        const float4 v2 = *(const float4*)(base + 2176);
        const float4 v3 = *(const float4*)(base + 3264);
        f32x4 r;
        r[0] = (v0.x + v1.x + v2.x + v3.x) * (1.0f / 2048.0f);
        r[1] = (v0.y + v1.y + v2.y + v3.y) * (1.0f / 2048.0f);
        r[2] = (v0.z + v1.z + v2.z + v3.z) * (1.0f / 2048.0f);
        r[3] = (v0.w + v1.w + v2.w + v3.w) * (1.0f / 2048.0f);
        *reinterpret_cast<f32x4*>(out + ((size_t)(b * N_ + i0 + row)) * D_ + c4) = r;
    }
}

// ---------------------------------------------------------------------------
// Fallback two-kernel path (v10, proven 171.2 us) in case cooperative launch
// is rejected during graph capture.
// ---------------------------------------------------------------------------
__global__ __launch_bounds__(256) void ex_kernel(
    const float* __restrict__ x,
    const float* __restrict__ W,
    const float* __restrict__ bias,
    __hip_bfloat16* __restrict__ e_hi,
    __hip_bfloat16* __restrict__ e_lo,
    __hip_bfloat16* __restrict__ e_hiT)
{
    __shared__ __align__(16) __hip_bfloat16 sW[2 * 64 * LDW];  // 34.8 KB
    __hip_bfloat16* sWhi = sW;
    __hip_bfloat16* sWlo = sW + 64 * LDW;

    const int tid  = threadIdx.x;
#pragma unroll
    for (int p = 0; p < 4; p++) {
        const int q = tid + p * 256;
        const int r = q >> 4, c = (q & 15) * 8;
        bf16x8 hi, lo;
        split8(W + (size_t)r * CIN_ + c, hi, lo);
        st_frag(sWhi + r * LDW + c, hi);
        st_frag(sWlo + r * LDW + c, lo);
    }
    __syncthreads();

    const int w    = tid >> 6;
    const int lane = tid & 63;
    const int quad = lane >> 4;
    const int l16  = lane & 15;
    const int m0   = blockIdx.x * 64 + w * 16;

    const float* xrow = x + (size_t)(m0 + l16) * CIN_;
    bf16x8 ah[4], al[4];
#pragma unroll
    for (int ks = 0; ks < 4; ks++)
        split8(xrow + ks * 32 + quad * 8, ah[ks], al[ks]);

    f32x4 acc[4];
#pragma unroll
    for (int nt = 0; nt < 4; nt++) acc[nt] = f32x4{0.f, 0.f, 0.f, 0.f};

#pragma unroll
    for (int ks = 0; ks < 4; ks++) {
#pragma unroll
        for (int nt = 0; nt < 4; nt++) {
            bf16x8 wh = ld_frag(sWhi + (nt * 16 + l16) * LDW + ks * 32 + quad * 8);
            bf16x8 wl = ld_frag(sWlo + (nt * 16 + l16) * LDW + ks * 32 + quad * 8);
            acc[nt] = __builtin_amdgcn_mfma_f32_16x16x32_bf16(ah[ks], wh, acc[nt], 0, 0, 0);
            acc[nt] = __builtin_amdgcn_mfma_f32_16x16x32_bf16(ah[ks], wl, acc[nt], 0, 0, 0);
            acc[nt] = __builtin_amdgcn_mfma_f32_16x16x32_bf16(al[ks], wh, acc[nt], 0, 0, 0);
        }
    }

#pragma unroll
    for (int nt = 0; nt < 4; nt++) {
        const int chan = nt * 16 + l16;
        const float bv = bias[chan];
        union { __hip_bfloat16 hh[4]; uint2 u2; } hv;
#pragma unroll
        for (int i = 0; i < 4; i++) {
            const int gr = m0 + quad * 4 + i;
            const float e = acc[nt][i] + bv;
            const __hip_bfloat16 hi = __float2bfloat16(e);
            const __hip_bfloat16 lo = __float2bfloat16(e - __bfloat162float(hi));
            e_hi[(size_t)gr * D_ + chan] = hi;
            e_lo[(size_t)gr * D_ + chan] = lo;
            hv.hh[i] = hi;
        }
        const int gr0 = m0 + quad * 4;
        const int bt = gr0 >> 11, ir = gr0 & (N_ - 1);
        *reinterpret_cast<uint2*>(e_hiT + ((size_t)bt * D_ + chan) * N_ + ir) = hv.u2;
    }
}

__global__ __launch_bounds__(512, 4) void fused_kernel(
    const __hip_bfloat16* __restrict__ e_hi,
    const __hip_bfloat16* __restrict__ e_lo,
    const __hip_bfloat16* __restrict__ e_hiT,
    float* __restrict__ out)
{
    __shared__ __align__(16) unsigned char smem[32 * LDF * 4 + 128 * LDE * 2 * 2 + 64 * LDT * 2];
    float*          sLpF  = (float*)smem;
    __hip_bfloat16* sEhi  = (__hip_bfloat16*)(smem + 32 * LDF * 4);
    __hip_bfloat16* sElo  = sEhi + 128 * LDE;
    __hip_bfloat16* sEhiT = sElo + 128 * LDE;

    const int b   = blockIdx.x;
    const int i0  = blockIdx.y * 32;
    const int tid = threadIdx.x;
    const int w = tid >> 6, lane = tid & 63, quad = lane >> 4, l16 = lane & 15;
    const int g = w >> 2, h = w & 3;
    const int m0 = i0 + g * 16;
    const int koff = h * 32 + quad * 8;

    const int q2 = tid + 512;
    const int er1 = tid >> 3, ec1 = (tid & 7) * 8;
    const int er2 = q2  >> 3, ec2 = (q2  & 7) * 8;
    const int tr1 = tid >> 4, tc1 = (tid & 15) * 8;
    const int tr2 = q2  >> 4, tc2 = (q2  & 15) * 8;

    const __hip_bfloat16* eih = e_hi + (size_t)(b * N_ + m0 + l16) * D_;
    const __hip_bfloat16* eil = e_lo + (size_t)(b * N_ + m0 + l16) * D_;
    bf16x8 ahi[2], alo[2];
#pragma unroll
    for (int ks = 0; ks < 2; ks++) {
        ahi[ks] = ld_frag(eih + ks * 32 + quad * 8);
        alo[ks] = ld_frag(eil + ks * 32 + quad * 8);
    }

    f32x4 o[4];
#pragma unroll
    for (int nt = 0; nt < 4; nt++) o[nt] = f32x4{0.f, 0.f, 0.f, 0.f};

    float* lp_out = out + (size_t)B_ * N_ * D_;

    uint4 gh0, gh1, gl0, gl1, gt0, gt1;
    {
        gh0 = *(const uint4*)(e_hi + (size_t)(b * N_ + er1) * D_ + ec1);
        gh1 = *(const uint4*)(e_hi + (size_t)(b * N_ + er2) * D_ + ec2);
        gl0 = *(const uint4*)(e_lo + (size_t)(b * N_ + er1) * D_ + ec1);
        gl1 = *(const uint4*)(e_lo + (size_t)(b * N_ + er2) * D_ + ec2);
        gt0 = *(const uint4*)(e_hiT + (size_t)(b * D_ + tr1) * N_ + tc1);
        gt1 = *(const uint4*)(e_hiT + (size_t)(b * D_ + tr2) * N_ + tc2);
    }

    for (int jt = 0; jt < 16; jt++) {
        lds_barrier();

        if (jt > 0) {
            const int jc0 = (jt - 1) * 128;
#pragma unroll
            for (int p = 0; p < 2; p++) {
                const int q = tid + p * 512;
                const int r = q >> 5, c = (q & 31) * 4;
                __builtin_nontemporal_store(
                    *(const f32x4*)(sLpF + r * LDF + c),
                    (f32x4*)(lp_out + ((size_t)(b * N_ + i0 + r)) * N_ + jc0 + c));
            }
        }

        *(uint4*)(sEhi  + er1 * LDE + ec1) = gh0;
        *(uint4*)(sEhi  + er2 * LDE + ec2) = gh1;
        *(uint4*)(sElo  + er1 * LDE + ec1) = gl0;
        *(uint4*)(sElo  + er2 * LDE + ec2) = gl1;
        *(uint4*)(sEhiT + tr1 * LDT + tc1) = gt0;
        *(uint4*)(sEhiT + tr2 * LDT + tc2) = gt1;

        lds_barrier();

        {
            const int j0n = ((jt + 1) & 15) * 128;
            gh0 = *(const uint4*)(e_hi + (size_t)(b * N_ + j0n + er1) * D_ + ec1);
            gh1 = *(const uint4*)(e_hi + (size_t)(b * N_ + j0n + er2) * D_ + ec2);
            gl0 = *(const uint4*)(e_lo + (size_t)(b * N_ + j0n + er1) * D_ + ec1);
            gl1 = *(const uint4*)(e_lo + (size_t)(b * N_ + j0n + er2) * D_ + ec2);
            gt0 = *(const uint4*)(e_hiT + (size_t)(b * D_ + tr1) * N_ + j0n + tc1);
            gt1 = *(const uint4*)(e_hiT + (size_t)(b * D_ + tr2) * N_ + j0n + tc2);
        }

#pragma unroll
        for (int ntl = 0; ntl < 2; ntl++) {
            const int n0 = h * 32 + ntl * 16;
            f32x4 s = f32x4{0.f, 0.f, 0.f, 0.f};
#pragma unroll
            for (int ks = 0; ks < 2; ks++) {
                const int ko = ks * 32 + quad * 8;
                bf16x8 bhi = ld_frag(sEhi + (n0 + l16) * LDE + ko);
                bf16x8 blo = ld_frag(sElo + (n0 + l16) * LDE + ko);
                s = __builtin_amdgcn_mfma_f32_16x16x32_bf16(ahi[ks], bhi, s, 0, 0, 0);
                s = __builtin_amdgcn_mfma_f32_16x16x32_bf16(ahi[ks], blo, s, 0, 0, 0);
                s = __builtin_amdgcn_mfma_f32_16x16x32_bf16(alo[ks], bhi, s, 0, 0, 0);
            }
#pragma unroll
            for (int i = 0; i < 4; i++) {
                const float tc = fmaxf(s[i], 0.0f);
                const float z = __builtin_amdgcn_exp2f(tc * -2.8853900817779268f);
                const float v = (1.0f - z) * __builtin_amdgcn_rcpf(1.0f + z);
                sLpF[(g * 16 + quad * 4 + i) * LDF + n0 + l16] = v;
            }
        }

        {
            bf16x8 a = cvt8(sLpF + (g * 16 + l16) * LDF + koff);
#pragma unroll
            for (int nt = 0; nt < 4; nt++) {
                bf16x8 bfr = ld_frag(sEhiT + (nt * 16 + l16) * LDT + koff);
                o[nt] = __builtin_amdgcn_mfma_f32_16x16x32_bf16(a, bfr, o[nt], 0, 0, 0);
            }
        }
    }

    lds_barrier();
    {
        const int jc0 = 15 * 128;
#pragma unroll
        for (int p = 0; p < 2; p++) {
            const int q = tid + p * 512;
            const int r = q >> 5, c = (q & 31) * 4;
            __builtin_nontemporal_store(
                *(const f32x4*)(sLpF + r * LDF + c),
                (f32x4*)(lp_out + ((size_t)(b * N_ + i0 + r)) * N_ + jc0 + c));
        }
    }
    lds_barrier();

    float* sO = (float*)smem;
#pragma unroll
    for (int nt = 0; nt < 4; nt++) {
#pragma unroll
        for (int i = 0; i < 4; i++) {
            const int row = quad * 4 + i;
            const int chan = nt * 16 + l16;
            sO[w * 1088 + row * 68 + chan] = o[nt][i];
        }
    }
    lds_barrier();
    {
        const int row = tid >> 4;
        const int c4  = (tid & 15) * 4;
        const int gg = row >> 4, rr = row & 15;
        const float* base = sO + (gg * 4) * 1088 + rr * 68 + c4;
        const float4 v0 = *(const float4*)(base);
        const float4 v1 = *(const float4*)(base + 1088);
        const float4 v2 = *(const float4*)(base + 2176);
        const float4 v3 = *(const float4*)(base + 3264);
        f32x4 r;
        r[0] = (v0.x + v1.x + v2.x + v3.x) * (1.0f / 2048.0f);
        r[1] = (v0.y + v1.y + v2.y + v3.y) * (1.0f / 2048.0f);
        r[2] = (v0.z + v1.z + v2.z + v3.z) * (1.0f / 2048.0f);
        r[3] = (v0.w + v1.w + v2.w + v3.w) * (1.0f / 2048.0f);
        *reinterpret_cast<f32x4*>(out + ((size_t)(b * N_ + i0 + row)) * D_ + c4) = r;
    }
}

// ---------------------------------------------------------------------------
extern "C" void kernel_launch(void* const* d_in, const int* in_sizes, int n_in,
                              void* d_out, int out_size, void* d_ws, size_t ws_size,
                              hipStream_t stream) {
    const float* x    = (const float*)d_in[0];
    const float* W    = (const float*)d_in[1];
    const float* bias = (const float*)d_in[2];
    float* out = (float*)d_out;

    __hip_bfloat16* e_hi  = (__hip_bfloat16*)d_ws;            // [B*N][64]
    __hip_bfloat16* e_lo  = e_hi + (size_t)B_ * N_ * D_;      // [B*N][64]
    __hip_bfloat16* e_hiT = e_lo + (size_t)B_ * N_ * D_;      // [B][64][N]

    void* args[] = {(void*)&x, (void*)&W, (void*)&bias,
                    (void*)&e_hi, (void*)&e_lo, (void*)&e_hiT, (void*)&out};
    hipError_t err = hipLaunchCooperativeKernel(
        reinterpret_cast<const void*>(merged_kernel),
        dim3(8, 64), dim3(512), args, 0, stream);
    if (err != hipSuccess) {
        // Fallback: proven two-kernel v10 path.
        ex_kernel<<<dim3(256), dim3(256), 0, stream>>>(x, W, bias, e_hi, e_lo, e_hiT);
        fused_kernel<<<dim3(8, 64), dim3(512), 0, stream>>>(e_hi, e_lo, e_hiT, out);
    }
}

// Round 11
// 171.902 us; speedup vs baseline: 1.8483x; 1.8483x over previous
//
#include <hip/hip_runtime.h>
#include <hip/hip_bf16.h>

// LPLayer: e = x@W^T + b; lp = relu(tanh(e@e^T)); nf = lp@e / N
// B=8, N=2048, C_IN=128, D(C_OUT)=64. All I/O **fp32** (reference dtypes).
// d_out (float) = [nf (8*2048*64)] ++ [lp (8*2048*2048)]
//
// v12 = v10 verbatim (session best, 171.2 us). v11's cooperative merge
// regressed 171->318: grid-wide fusion broke the batch<->XCD L2 alignment
// (phase-2 panel reads paid cross-XCD coherence on every staged prefetch;
// FETCH 3.1->7.4 MB, bank conflicts 2.5->5.8 M, loop 3.5x slower). The
// two-kernel form keeps batch-b blocks on XCD b and panels L2-local.
// Confirmed-lever ledger baked into this kernel:
//   * LDS-staged E panels + ds_read frags (beats direct-L2 gathers ~2x);
//   * lp stores in >=512 B contiguous chunks (DRAM write pattern lever);
//   * T14 reg-staged panel loads: issue right after Bb, ds_write next Ba;
//   * lgkm-only barriers: NT stores/prefetches never vmcnt-drained in-loop.

#define B_    8
#define N_    2048
#define D_    64
#define CIN_  128

typedef __bf16 bf16x8 __attribute__((ext_vector_type(8)));
typedef float f32x4  __attribute__((ext_vector_type(4)));

union FragU { uint4 u; bf16x8 f; };

static __device__ __forceinline__ bf16x8 ld_frag(const __hip_bfloat16* p) {
    FragU fu; fu.u = *reinterpret_cast<const uint4*>(p); return fu.f;
}

static __device__ __forceinline__ void st_frag(__hip_bfloat16* p, bf16x8 f) {
    FragU fu; fu.f = f; *reinterpret_cast<uint4*>(p) = fu.u;
}

// Split 8 consecutive fp32 into hi/lo bf16x8 (hi = RTN(v), lo = RTN(v - hi)).
static __device__ __forceinline__ void split8(const float* p, bf16x8& hi, bf16x8& lo) {
    const float4 a = *reinterpret_cast<const float4*>(p);
    const float4 b = *reinterpret_cast<const float4*>(p + 4);
    const float v[8] = {a.x, a.y, a.z, a.w, b.x, b.y, b.z, b.w};
#pragma unroll
    for (int i = 0; i < 8; i++) {
        const __bf16 h = (__bf16)v[i];
        hi[i] = h;
        lo[i] = (__bf16)(v[i] - (float)h);
    }
}

// Convert 8 consecutive fp32 (LDS) to bf16x8.
static __device__ __forceinline__ bf16x8 cvt8(const float* p) {
    const float4 a = *reinterpret_cast<const float4*>(p);
    const float4 b = *reinterpret_cast<const float4*>(p + 4);
    bf16x8 r;
    r[0] = (__bf16)a.x; r[1] = (__bf16)a.y; r[2] = (__bf16)a.z; r[3] = (__bf16)a.w;
    r[4] = (__bf16)b.x; r[5] = (__bf16)b.y; r[6] = (__bf16)b.z; r[7] = (__bf16)b.w;
    return r;
}

// Barrier that waits ONLY on LDS ops (lgkmcnt), never vmcnt: in-flight
// prefetch loads and NT store drains survive across it. sched_barrier(0)
// stops post-barrier LDS reads hoisting above (rule #18).
static __device__ __forceinline__ void lds_barrier() {
    asm volatile("s_waitcnt lgkmcnt(0)" ::: "memory");
    __builtin_amdgcn_s_barrier();
    __builtin_amdgcn_sched_barrier(0);
}

// ---------------------------------------------------------------------------
// Kernel 1: e = x @ W^T + b (fp32 in), emit e_hi/e_lo (bf16 split) and
// e_hiT ([B][64][N] transposed bf16 for K2's PV B-operand).
// Split-MFMA: e = xh*wh + xh*wl + xl*wh  (error ~4e-6).
// Grid: 256 blocks x 256 thr (4 waves); wave = 16 rows x 64 chans.
// W hi/lo split staged ONCE per block into LDS; e_hiT stores packed 8 B.
// ---------------------------------------------------------------------------
#define LDW  136  // W LDS row stride, bf16 elems (128 + 8 pad -> 2-way banks)

__global__ __launch_bounds__(256) void ex_kernel(
    const float* __restrict__ x,
    const float* __restrict__ W,
    const float* __restrict__ bias,
    __hip_bfloat16* __restrict__ e_hi,
    __hip_bfloat16* __restrict__ e_lo,
    __hip_bfloat16* __restrict__ e_hiT)
{
    __shared__ __align__(16) __hip_bfloat16 sW[2 * 64 * LDW];  // 34.8 KB
    __hip_bfloat16* sWhi = sW;
    __hip_bfloat16* sWlo = sW + 64 * LDW;

    const int tid  = threadIdx.x;

    // ---- stage W split into LDS: 64 rows x 128, 1024 chunks of 8 ----
#pragma unroll
    for (int p = 0; p < 4; p++) {
        const int q = tid + p * 256;
        const int r = q >> 4, c = (q & 15) * 8;
        bf16x8 hi, lo;
        split8(W + (size_t)r * CIN_ + c, hi, lo);
        st_frag(sWhi + r * LDW + c, hi);
        st_frag(sWlo + r * LDW + c, lo);
    }
    __syncthreads();

    const int w    = tid >> 6;
    const int lane = tid & 63;
    const int quad = lane >> 4;
    const int l16  = lane & 15;
    const int m0   = blockIdx.x * 64 + w * 16;   // 16 rows per wave

    // A-frags: A[m=lane&15][k=quad*8+j], 4 ksteps over K=128
    const float* xrow = x + (size_t)(m0 + l16) * CIN_;
    bf16x8 ah[4], al[4];
#pragma unroll
    for (int ks = 0; ks < 4; ks++)
        split8(xrow + ks * 32 + quad * 8, ah[ks], al[ks]);

    f32x4 acc[4];
#pragma unroll
    for (int nt = 0; nt < 4; nt++) acc[nt] = f32x4{0.f, 0.f, 0.f, 0.f};

#pragma unroll
    for (int ks = 0; ks < 4; ks++) {
#pragma unroll
        for (int nt = 0; nt < 4; nt++) {
            bf16x8 wh = ld_frag(sWhi + (nt * 16 + l16) * LDW + ks * 32 + quad * 8);
            bf16x8 wl = ld_frag(sWlo + (nt * 16 + l16) * LDW + ks * 32 + quad * 8);
            acc[nt] = __builtin_amdgcn_mfma_f32_16x16x32_bf16(ah[ks], wh, acc[nt], 0, 0, 0);
            acc[nt] = __builtin_amdgcn_mfma_f32_16x16x32_bf16(ah[ks], wl, acc[nt], 0, 0, 0);
            acc[nt] = __builtin_amdgcn_mfma_f32_16x16x32_bf16(al[ks], wh, acc[nt], 0, 0, 0);
        }
    }

    // Epilogue: bias, hi/lo split, stores. C/D: col=lane&15 (chan), row=quad*4+reg.
#pragma unroll
    for (int nt = 0; nt < 4; nt++) {
        const int chan = nt * 16 + l16;
        const float bv = bias[chan];
        union { __hip_bfloat16 h[4]; uint2 u2; } hv;
#pragma unroll
        for (int i = 0; i < 4; i++) {
            const int gr = m0 + quad * 4 + i;          // global row in [0, B*N)
            const float e = acc[nt][i] + bv;
            const __hip_bfloat16 hi = __float2bfloat16(e);
            const __hip_bfloat16 lo = __float2bfloat16(e - __bfloat162float(hi));
            e_hi[(size_t)gr * D_ + chan] = hi;
            e_lo[(size_t)gr * D_ + chan] = lo;
            hv.h[i] = hi;
        }
        // 4 consecutive ir rows (quad*4..+3, same bt always) -> one 8 B store
        const int gr0 = m0 + quad * 4;
        const int bt = gr0 >> 11, ir = gr0 & (N_ - 1);
        *reinterpret_cast<uint2*>(e_hiT + ((size_t)bt * D_ + chan) * N_ + ir) = hv.u2;
    }
}

// ---------------------------------------------------------------------------
// Kernel 2: fused Gram + tanh/relu + fp32 lp store + PV accumulate + nf store.
// Phase order per jt:  Ba -> [store lp(jt-1) from sLpF || ds_write panel jt]
//   -> Bb -> issue loads(jt+1) -> Gram(jt) -> trans(jt)->sLpF -> PV(jt).
// Race check: Ba fences {Gram/PV panel reads, trans sLpF writes} of jt-1
// before {panel writes, sLpF store-reads}; Bb fences those before
// {Gram reads, trans writes} of jt. PV self-reads its own 16x32 sLpF block
// (same-wave RAW, verified v8/v9). Store phase for jt=15 after the loop.
// LDS 71,168 B -> 2 blocks/CU (16 waves/CU).
// Gram split: S = Ahi*Bhi + Ahi*Blo + Alo*Bhi.
// Grid: (8 batches, 64 i-tiles) x 512 thr.
// ---------------------------------------------------------------------------
#define LDE  72   // E tile LDS row stride, bf16 (64 + 8 pad)
#define LDT  136  // EhiT LDS row stride, bf16 (128 + 8 pad)
#define LDF  132  // lp tile LDS row stride, fp32 (128 + 4 pad, 16B-mult)

__global__ __launch_bounds__(512, 4) void fused_kernel(
    const __hip_bfloat16* __restrict__ e_hi,
    const __hip_bfloat16* __restrict__ e_lo,
    const __hip_bfloat16* __restrict__ e_hiT,
    float* __restrict__ out)
{
    // 16896 (sLpF) + 18432*2 (sEhi/sElo) + 17408 (sEhiT) = 71,168 B
    __shared__ __align__(16) unsigned char smem[32 * LDF * 4 + 128 * LDE * 2 * 2 + 64 * LDT * 2];
    float*          sLpF  = (float*)smem;                           // [32][132] fp32
    __hip_bfloat16* sEhi  = (__hip_bfloat16*)(smem + 32 * LDF * 4); // [128][72]
    __hip_bfloat16* sElo  = sEhi + 128 * LDE;                       // [128][72]
    __hip_bfloat16* sEhiT = sElo + 128 * LDE;                       // [64][136]

    const int b   = blockIdx.x;          // batch (id%8: XCD-aligned)
    const int i0  = blockIdx.y * 32;
    const int tid = threadIdx.x;
    const int w = tid >> 6, lane = tid & 63, quad = lane >> 4, l16 = lane & 15;
    const int g = w >> 2, h = w & 3;
    const int m0 = i0 + g * 16;
    const int koff = h * 32 + quad * 8;  // wave's j/k quarter offset

    // Per-thread staging chunk assignments (1024 chunks of 16 B per array).
    const int q2 = tid + 512;
    const int er1 = tid >> 3, ec1 = (tid & 7) * 8;   // Ehi/Elo chunk 1
    const int er2 = q2  >> 3, ec2 = (q2  & 7) * 8;   // Ehi/Elo chunk 2
    const int tr1 = tid >> 4, tc1 = (tid & 15) * 8;  // EhiT chunk 1
    const int tr2 = q2  >> 4, tc2 = (q2  & 15) * 8;  // EhiT chunk 2

    // Persistent Ei A-frags (hi & lo), K=64 -> 2 ksteps
    const __hip_bfloat16* eih = e_hi + (size_t)(b * N_ + m0 + l16) * D_;
    const __hip_bfloat16* eil = e_lo + (size_t)(b * N_ + m0 + l16) * D_;
    bf16x8 ahi[2], alo[2];
#pragma unroll
    for (int ks = 0; ks < 2; ks++) {
        ahi[ks] = ld_frag(eih + ks * 32 + quad * 8);
        alo[ks] = ld_frag(eil + ks * 32 + quad * 8);
    }

    f32x4 o[4];
#pragma unroll
    for (int nt = 0; nt < 4; nt++) o[nt] = f32x4{0.f, 0.f, 0.f, 0.f};

    float* lp_out = out + (size_t)B_ * N_ * D_;

    // ---- preload staged panel regs for jt = 0 ----
    uint4 gh0, gh1, gl0, gl1, gt0, gt1;
    {
        gh0 = *(const uint4*)(e_hi + (size_t)(b * N_ + er1) * D_ + ec1);
        gh1 = *(const uint4*)(e_hi + (size_t)(b * N_ + er2) * D_ + ec2);
        gl0 = *(const uint4*)(e_lo + (size_t)(b * N_ + er1) * D_ + ec1);
        gl1 = *(const uint4*)(e_lo + (size_t)(b * N_ + er2) * D_ + ec2);
        gt0 = *(const uint4*)(e_hiT + (size_t)(b * D_ + tr1) * N_ + tc1);
        gt1 = *(const uint4*)(e_hiT + (size_t)(b * D_ + tr2) * N_ + tc2);
    }

    for (int jt = 0; jt < 16; jt++) {
        lds_barrier();   // Ba: jt-1's panel reads + trans writes complete

        // ---- lp(jt-1) -> global NT (512 B chunks), || with panel ds_write ----
        if (jt > 0) {
            const int jc0 = (jt - 1) * 128;
#pragma unroll
            for (int p = 0; p < 2; p++) {
                const int q = tid + p * 512;          // 0..1023
                const int r = q >> 5, c = (q & 31) * 4;
                __builtin_nontemporal_store(
                    *(const f32x4*)(sLpF + r * LDF + c),
                    (f32x4*)(lp_out + ((size_t)(b * N_ + i0 + r)) * N_ + jc0 + c));
            }
        }

        // ---- ds_write staged panel jt (counted vmcnt on reg deps) ----
        *(uint4*)(sEhi  + er1 * LDE + ec1) = gh0;
        *(uint4*)(sEhi  + er2 * LDE + ec2) = gh1;
        *(uint4*)(sElo  + er1 * LDE + ec1) = gl0;
        *(uint4*)(sElo  + er2 * LDE + ec2) = gl1;
        *(uint4*)(sEhiT + tr1 * LDT + tc1) = gt0;
        *(uint4*)(sEhiT + tr2 * LDT + tc2) = gt1;

        lds_barrier();   // Bb: panel jt visible; store-reads of jt-1 done

        // ---- issue staged loads for jt+1 (in flight through Gram/trans/PV) ----
        {
            const int j0n = ((jt + 1) & 15) * 128;    // wrap: harmless prefetch
            gh0 = *(const uint4*)(e_hi + (size_t)(b * N_ + j0n + er1) * D_ + ec1);
            gh1 = *(const uint4*)(e_hi + (size_t)(b * N_ + j0n + er2) * D_ + ec2);
            gl0 = *(const uint4*)(e_lo + (size_t)(b * N_ + j0n + er1) * D_ + ec1);
            gl1 = *(const uint4*)(e_lo + (size_t)(b * N_ + j0n + er2) * D_ + ec2);
            gt0 = *(const uint4*)(e_hiT + (size_t)(b * D_ + tr1) * N_ + j0n + tc1);
            gt1 = *(const uint4*)(e_hiT + (size_t)(b * D_ + tr2) * N_ + j0n + tc2);
        }

        // ---- Gram: S[16 x 32] per wave from LDS, split product, tanh/relu ----
#pragma unroll
        for (int ntl = 0; ntl < 2; ntl++) {
            const int n0 = h * 32 + ntl * 16;
            f32x4 s = f32x4{0.f, 0.f, 0.f, 0.f};
#pragma unroll
            for (int ks = 0; ks < 2; ks++) {
                const int ko = ks * 32 + quad * 8;
                bf16x8 bhi = ld_frag(sEhi + (n0 + l16) * LDE + ko);
                bf16x8 blo = ld_frag(sElo + (n0 + l16) * LDE + ko);
                s = __builtin_amdgcn_mfma_f32_16x16x32_bf16(ahi[ks], bhi, s, 0, 0, 0);
                s = __builtin_amdgcn_mfma_f32_16x16x32_bf16(ahi[ks], blo, s, 0, 0, 0);
                s = __builtin_amdgcn_mfma_f32_16x16x32_bf16(alo[ks], bhi, s, 0, 0, 0);
            }
#pragma unroll
            for (int i = 0; i < 4; i++) {
                // relu(tanh(t)) = tanh(max(t,0)) — clamp BEFORE exp2: no
                // overflow path, and fmaxf(NaN,0)=0 absorbs upstream garbage.
                const float tc = fmaxf(s[i], 0.0f);
                const float z = __builtin_amdgcn_exp2f(tc * -2.8853900817779268f);
                const float v = (1.0f - z) * __builtin_amdgcn_rcpf(1.0f + z);
                sLpF[(g * 16 + quad * 4 + i) * LDF + n0 + l16] = v;
            }
        }

        // ---- PV: self-read own 16x32 block (same-wave RAW) + sEhiT frags ----
        {
            bf16x8 a = cvt8(sLpF + (g * 16 + l16) * LDF + koff);
#pragma unroll
            for (int nt = 0; nt < 4; nt++) {
                bf16x8 bfr = ld_frag(sEhiT + (nt * 16 + l16) * LDT + koff);
                o[nt] = __builtin_amdgcn_mfma_f32_16x16x32_bf16(a, bfr, o[nt], 0, 0, 0);
            }
        }
    }

    // ---- drain: store lp tile 15 ----
    lds_barrier();
    {
        const int jc0 = 15 * 128;
#pragma unroll
        for (int p = 0; p < 2; p++) {
            const int q = tid + p * 512;
            const int r = q >> 5, c = (q & 31) * 4;
            __builtin_nontemporal_store(
                *(const f32x4*)(sLpF + r * LDF + c),
                (f32x4*)(lp_out + ((size_t)(b * N_ + i0 + r)) * N_ + jc0 + c));
        }
    }
    lds_barrier();   // store-reads done before sO overlay

    // ---- epilogue: sum 4 j-quarter partials, /N, store node_feats (fp32) ----
    float* sO = (float*)smem;   // overlay (34.8 KB)
#pragma unroll
    for (int nt = 0; nt < 4; nt++) {
#pragma unroll
        for (int i = 0; i < 4; i++) {
            const int row = quad * 4 + i;            // local row in group
            const int chan = nt * 16 + l16;
            sO[w * 1088 + row * 68 + chan] = o[nt][i];   // stride 68: 2-way banks
        }
    }
    lds_barrier();
    {
        const int row = tid >> 4;                    // 0..31
        const int c4  = (tid & 15) * 4;
        const int gg = row >> 4, rr = row & 15;
        const float* base = sO + (gg * 4) * 1088 + rr * 68 + c4;
        const float4 v0 = *(const float4*)(base);
        const float4 v1 = *(const float4*)(base + 1088);
        const float4 v2 = *(const float4*)(base + 2176);
        const float4 v3 = *(const float4*)(base + 3264);
        f32x4 r;
        r[0] = (v0.x + v1.x + v2.x + v3.x) * (1.0f / 2048.0f);
        r[1] = (v0.y + v1.y + v2.y + v3.y) * (1.0f / 2048.0f);
        r[2] = (v0.z + v1.z + v2.z + v3.z) * (1.0f / 2048.0f);
        r[3] = (v0.w + v1.w + v2.w + v3.w) * (1.0f / 2048.0f);
        *reinterpret_cast<f32x4*>(out + ((size_t)(b * N_ + i0 + row)) * D_ + c4) = r;
    }
}

// ---------------------------------------------------------------------------
extern "C" void kernel_launch(void* const* d_in, const int* in_sizes, int n_in,
                              void* d_out, int out_size, void* d_ws, size_t ws_size,
                              hipStream_t stream) {
    const float* x    = (const float*)d_in[0];
    const float* W    = (const float*)d_in[1];
    const float* bias = (const float*)d_in[2];
    float* out = (float*)d_out;

    __hip_bfloat16* e_hi  = (__hip_bfloat16*)d_ws;            // [B*N][64]
    __hip_bfloat16* e_lo  = e_hi + (size_t)B_ * N_ * D_;      // [B*N][64]
    __hip_bfloat16* e_hiT = e_lo + (size_t)B_ * N_ * D_;      // [B][64][N]

    ex_kernel<<<dim3(256), dim3(256), 0, stream>>>(x, W, bias, e_hi, e_lo, e_hiT);
    fused_kernel<<<dim3(8, 64), dim3(512), 0, stream>>>(e_hi, e_lo, e_hiT, out);
}